// Round 1
// baseline (33.407 us; speedup 1.0000x reference)
//
#include <hip/hip_runtime.h>
#include <math.h>

#define B_  4
#define CI  8
#define HH  128
#define WW  128
#define CO  16
#define KH  5
#define KW  5
#define HO  124
#define WO  124

#define TX  32   // output cols per block
#define TY  8    // output rows per block
// threads: 8 x-groups (4 px each) * 8 rows * 4 o-groups (4 o each) = 256

__global__ __launch_bounds__(256)
void maxplus_conv_kernel(const float* __restrict__ img,
                         const float* __restrict__ kern,
                         float* __restrict__ out)
{
    // weights, flipped, laid out [c][i][j][o] so 4 consecutive o = float4 broadcast
    __shared__ __align__(16) float wlds[CI * KH * KW * CO];          // 3200 f = 12.8 KB
    // img tile: rows y0..y0+11, cols x0..x0+35, -INF padded outside image
    __shared__ __align__(16) float ilds[CI][TY + KH - 1][TX + KW - 1 + 1]; // [8][12][36] = 13.8 KB

    const int tid = threadIdx.x;
    const int x0  = blockIdx.x * TX;
    const int y0  = blockIdx.y * TY;
    const int b   = blockIdx.z;

    // ---- stage flipped weights ----
    for (int idx = tid; idx < CI * KH * KW * CO; idx += 256) {
        const int o = idx & 15;
        const int r = idx >> 4;
        const int j = r % 5;
        const int i = (r / 5) % 5;
        const int c = r / 25;
        wlds[idx] = kern[((o * CI + c) * KH + (4 - i)) * KW + (4 - j)];
    }

    // ---- stage img tile (coalesced along cols), -INF outside ----
    const float* imgb = img + (size_t)b * CI * HH * WW;
    for (int idx = tid; idx < CI * 12 * 36; idx += 256) {
        const int col = idx % 36;
        const int r   = (idx / 36) % 12;
        const int c   = idx / (36 * 12);
        const int gy = y0 + r, gx = x0 + col;
        float v = -INFINITY;
        if (gy < HH && gx < WW) v = imgb[(c * HH + gy) * WW + gx];
        ilds[c][r][col] = v;
    }
    __syncthreads();

    const int tx = tid & 7;          // x-group: cols x0 + tx*4 .. +3
    const int ty = (tid >> 3) & 7;   // output row y0 + ty
    const int o0 = (tid >> 6) << 2;  // o-group: o0 .. o0+3

    float acc[4][4]; // [px][oo]
    #pragma unroll
    for (int p = 0; p < 4; ++p)
        #pragma unroll
        for (int q = 0; q < 4; ++q) acc[p][q] = -INFINITY;

    for (int c = 0; c < CI; ++c) {
        #pragma unroll
        for (int i = 0; i < KH; ++i) {
            const float* vp = &ilds[c][ty + i][tx * 4];
            const float4 va = *(const float4*)vp;
            const float4 vb = *(const float4*)(vp + 4);
            const float v[8] = {va.x, va.y, va.z, va.w, vb.x, vb.y, vb.z, vb.w};
            #pragma unroll
            for (int j = 0; j < KW; ++j) {
                const float4 wv = *(const float4*)&wlds[(((c * KH + i) * KW + j) << 4) + o0];
                const float wa[4] = {wv.x, wv.y, wv.z, wv.w};
                #pragma unroll
                for (int p = 0; p < 4; ++p)
                    #pragma unroll
                    for (int q = 0; q < 4; ++q)
                        acc[p][q] = fmaxf(acc[p][q], v[p + j] + wa[q]);
            }
        }
    }

    // ---- write out ----
    const int y = y0 + ty;
    if (y < HO) {
        #pragma unroll
        for (int q = 0; q < 4; ++q) {
            const int o = o0 + q;
            float* op = out + (((size_t)b * CO + o) * HO + y) * WO;
            #pragma unroll
            for (int p = 0; p < 4; ++p) {
                const int x = x0 + tx * 4 + p;
                if (x < WO) op[x] = acc[p][q];
            }
        }
    }
}

extern "C" void kernel_launch(void* const* d_in, const int* in_sizes, int n_in,
                              void* d_out, int out_size, void* d_ws, size_t ws_size,
                              hipStream_t stream)
{
    const float* img  = (const float*)d_in[0];
    const float* kern = (const float*)d_in[1];
    float* out = (float*)d_out;

    dim3 grid((WO + TX - 1) / TX, (HO + TY - 1) / TY, B_);  // 4 x 16 x 4 = 256 blocks
    dim3 block(256);
    maxplus_conv_kernel<<<grid, block, 0, stream>>>(img, kern, out);
}

// Round 2
// 16.078 us; speedup vs baseline: 2.0779x; 2.0779x over previous
//
#include <hip/hip_runtime.h>
#include <math.h>

#define B_  4
#define CI  8
#define HH  128
#define WW  128
#define CO  16
#define KH  5
#define KW  5
#define HO  124
#define WO  124

#define TX  32   // output cols per block (8 x-groups of 4 px)
#define TY  8    // output rows per block
#define THREADS 512  // 8 tx * 8 ty * 8 o-groups(waves); each wave owns 2 output channels

__global__ __launch_bounds__(THREADS)
void maxplus_conv2(const float* __restrict__ img,
                   const float* __restrict__ kern,
                   float* __restrict__ out)
{
    // img tile: rows y0..y0+11, cols x0..x0+35, -INF padded outside image
    __shared__ __align__(16) float ilds[CI][TY + KH - 1][TX + KW - 1]; // [8][12][36] = 13.8 KB

    const int tid = threadIdx.x;
    const int x0  = blockIdx.x * TX;
    const int y0  = blockIdx.y * TY;
    const int b   = blockIdx.z;

    // ---- stage img tile (coalesced along cols), -INF outside ----
    const float* imgb = img + (size_t)b * CI * HH * WW;
    for (int idx = tid; idx < CI * 12 * 36; idx += THREADS) {
        const int col = idx % 36;
        const int t   = idx / 36;
        const int r   = t % 12;
        const int c   = t / 12;
        const int gy = y0 + r, gx = x0 + col;
        float v = -INFINITY;
        if (gy < HH && gx < WW) v = imgb[(c * HH + gy) * WW + gx];
        ilds[c][r][col] = v;
    }
    __syncthreads();

    const int tx = tid & 7;          // x-group: cols x0 + tx*4 .. +3
    const int ty = (tid >> 3) & 7;   // output row y0 + ty
    // wave-uniform output-channel pair: wave w handles o = 2w, 2w+1.
    // readfirstlane forces SGPR -> weight addresses are provably uniform
    // -> scalar s_load from the 12.8KB K$-resident kernel (no LDS, no VALU).
    const int o0 = __builtin_amdgcn_readfirstlane((tid >> 6) << 1);

    float acc[4][2]; // [px][oo]
    #pragma unroll
    for (int p = 0; p < 4; ++p) {
        acc[p][0] = -INFINITY;
        acc[p][1] = -INFINITY;
    }

    // process input channels in PAIRS so each acc gets 2 new terms per step
    // -> fmaxf(fmaxf(acc,t0),t1) fuses to v_max3_f32
    #pragma unroll 1
    for (int cp = 0; cp < CI / 2; ++cp) {
        const int c0 = cp * 2, c1 = cp * 2 + 1;
        #pragma unroll
        for (int i = 0; i < KH; ++i) {
            const float* p0 = &ilds[c0][ty + i][tx * 4];
            const float* p1 = &ilds[c1][ty + i][tx * 4];
            const float4 a0 = *(const float4*)(p0);
            const float4 a1 = *(const float4*)(p0 + 4);
            const float4 b0 = *(const float4*)(p1);
            const float4 b1 = *(const float4*)(p1 + 4);
            const float v0[8] = {a0.x, a0.y, a0.z, a0.w, a1.x, a1.y, a1.z, a1.w};
            const float v1[8] = {b0.x, b0.y, b0.z, b0.w, b1.x, b1.y, b1.z, b1.w};
            #pragma unroll
            for (int j = 0; j < KW; ++j) {
                // flipped tap: kern[o][c][4-i][4-j]; all indices wave-uniform
                const int wi = (4 - i) * KW + (4 - j);
                const float w00 = kern[(o0 * CI + c0) * (KH * KW) + wi];
                const float w01 = kern[((o0 + 1) * CI + c0) * (KH * KW) + wi];
                const float w10 = kern[(o0 * CI + c1) * (KH * KW) + wi];
                const float w11 = kern[((o0 + 1) * CI + c1) * (KH * KW) + wi];
                #pragma unroll
                for (int p = 0; p < 4; ++p) {
                    acc[p][0] = fmaxf(fmaxf(acc[p][0], v0[p + j] + w00), v1[p + j] + w10);
                    acc[p][1] = fmaxf(fmaxf(acc[p][1], v0[p + j] + w01), v1[p + j] + w11);
                }
            }
        }
    }

    // ---- write out: float4 per output channel (WO=124, x either fully in or out) ----
    const int y = y0 + ty;
    const int x = x0 + tx * 4;
    if (y < HO && x < WO) {
        #pragma unroll
        for (int q = 0; q < 2; ++q) {
            const int o = o0 + q;
            float4 st;
            st.x = acc[0][q]; st.y = acc[1][q]; st.z = acc[2][q]; st.w = acc[3][q];
            *(float4*)&out[(((size_t)b * CO + o) * HO + y) * WO + x] = st;
        }
    }
}

extern "C" void kernel_launch(void* const* d_in, const int* in_sizes, int n_in,
                              void* d_out, int out_size, void* d_ws, size_t ws_size,
                              hipStream_t stream)
{
    const float* img  = (const float*)d_in[0];
    const float* kern = (const float*)d_in[1];
    float* out = (float*)d_out;

    dim3 grid((WO + TX - 1) / TX, (HO + TY - 1) / TY, B_);  // 4 x 16 x 4 = 256 blocks
    dim3 block(THREADS);
    maxplus_conv2<<<grid, block, 0, stream>>>(img, kern, out);
}

// Round 3
// 15.342 us; speedup vs baseline: 2.1775x; 1.0480x over previous
//
#include <hip/hip_runtime.h>
#include <math.h>

#define B_  4
#define CI  8
#define HH  128
#define WW  128
#define CO  16
#define KH  5
#define KW  5
#define HO  124
#define WO  124

#define TX  32
#define TY  8
#define THREADS 512   // 8 tx-groups * 8 rows * 8 waves (each wave owns an o-pair)

__global__ __launch_bounds__(THREADS)
void maxplus_conv3(const float* __restrict__ img,
                   const float* __restrict__ kern,
                   float* __restrict__ out)
{
    // img tile rows y0..y0+11, cols x0..x0+35, -INF padded. [8][12][36] = 13.8 KB
    __shared__ __align__(16) float ilds[CI][TY + KH - 1][TX + KW - 1];

    const int tid = threadIdx.x;
    const int x0  = blockIdx.x * TX;
    const int y0  = blockIdx.y * TY;
    const int b   = blockIdx.z;

    // ---- stage img tile as float4 chunks: 8c * 12r * 9 float4 = 864 ----
    const float* imgb = img + (size_t)b * CI * HH * WW;
    #pragma unroll
    for (int it = 0; it < 2; ++it) {
        const int idx = tid + it * THREADS;
        if (idx < 864) {
            const int c   = idx / 108;          // magic-mul
            const int rem = idx - c * 108;
            const int r   = rem / 9;
            const int f4  = rem - r * 9;
            const int gy = y0 + r;
            const int gx = x0 + f4 * 4;
            float4 v;
            if (gy < HH && gx < WW) {           // gx<128 => gx+3<=127 (x0%32==0, f4<=7)
                v = *(const float4*)&imgb[(c * HH + gy) * WW + gx];
            } else {
                v.x = v.y = v.z = v.w = -INFINITY;
            }
            *(float4*)&ilds[c][r][f4 * 4] = v;
        }
    }
    __syncthreads();

    const int tx = tid & 7;          // 4 px each
    const int ty = (tid >> 3) & 7;   // output row
    // wave-uniform o-pair; readfirstlane => provably uniform => s_load weights
    const int o0 = __builtin_amdgcn_readfirstlane((tid >> 6) << 1);

    const float* w0p = kern + (size_t)o0 * (CI * KH * KW);
    const float* w1p = w0p + CI * KH * KW;

    float2 acc[4];
    #pragma unroll
    for (int p = 0; p < 4; ++p) { acc[p].x = -INFINITY; acc[p].y = -INFINITY; }

    #pragma unroll 1
    for (int c = 0; c < CI; ++c) {
        // ---- bulk-hoist this channel's 50 weights (uniform -> clustered s_load) ----
        float w0[25], w1[25];
        #pragma unroll
        for (int t = 0; t < 25; ++t) {
            w0[t] = w0p[c * 25 + t];
            w1[t] = w1p[c * 25 + t];
        }
        // ---- bulk-preload this channel's img window (10 ds_read_b128) ----
        float4 va[5], vb[5];
        #pragma unroll
        for (int i = 0; i < KH; ++i) {
            const float* vp = &ilds[c][ty + i][tx * 4];
            va[i] = *(const float4*)vp;
            vb[i] = *(const float4*)(vp + 4);
        }
        // ---- pure-VALU compute ----
        #pragma unroll
        for (int i = 0; i < KH; ++i) {
            const float v[8] = {va[i].x, va[i].y, va[i].z, va[i].w,
                                vb[i].x, vb[i].y, vb[i].z, vb[i].w};
            #pragma unroll
            for (int p = 0; p < 4; ++p) {
                float2 T[5];
                #pragma unroll
                for (int j = 0; j < KW; ++j) {
                    const int wi = (4 - i) * KW + (4 - j);   // flipped tap, compile-time
                    T[j].x = v[p + j] + w0[wi];
                    T[j].y = v[p + j] + w1[wi];
                }
                // 2x max3 + 1x max per o
                const float m0x = fmaxf(fmaxf(T[0].x, T[1].x), T[2].x);
                const float m1x = fmaxf(T[3].x, T[4].x);
                acc[p].x = fmaxf(fmaxf(acc[p].x, m0x), m1x);
                const float m0y = fmaxf(fmaxf(T[0].y, T[1].y), T[2].y);
                const float m1y = fmaxf(T[3].y, T[4].y);
                acc[p].y = fmaxf(fmaxf(acc[p].y, m0y), m1y);
            }
        }
    }

    // ---- write out: float4 per output channel ----
    const int y = y0 + ty;
    const int x = x0 + tx * 4;
    if (y < HO && x < WO) {
        float4 s0, s1;
        s0.x = acc[0].x; s0.y = acc[1].x; s0.z = acc[2].x; s0.w = acc[3].x;
        s1.x = acc[0].y; s1.y = acc[1].y; s1.z = acc[2].y; s1.w = acc[3].y;
        *(float4*)&out[(((size_t)b * CO + o0) * HO + y) * WO + x] = s0;
        *(float4*)&out[(((size_t)b * CO + o0 + 1) * HO + y) * WO + x] = s1;
    }
}

extern "C" void kernel_launch(void* const* d_in, const int* in_sizes, int n_in,
                              void* d_out, int out_size, void* d_ws, size_t ws_size,
                              hipStream_t stream)
{
    const float* img  = (const float*)d_in[0];
    const float* kern = (const float*)d_in[1];
    float* out = (float*)d_out;

    dim3 grid((WO + TX - 1) / TX, (HO + TY - 1) / TY, B_);  // 4 x 16 x 4 = 256 blocks
    dim3 block(THREADS);
    maxplus_conv3<<<grid, block, 0, stream>>>(img, kern, out);
}

// Round 4
// 15.094 us; speedup vs baseline: 2.2132x; 1.0164x over previous
//
#include <hip/hip_runtime.h>
#include <math.h>

#define B_  4
#define CI  8
#define HH  128
#define WW  128
#define CO  16
#define KH  5
#define KW  5
#define HO  124
#define WO  124

#define TX  32
#define TY  8
#define THREADS 512   // 8 tx-groups * 8 rows * 8 waves; each wave owns ONE o

__global__ __launch_bounds__(THREADS, 4)
void maxplus_conv4(const float* __restrict__ img,
                   const float* __restrict__ kern,
                   float* __restrict__ out)
{
    // img tile rows y0..y0+11, cols x0..x0+35, -INF padded. [8][12][36] = 13.8 KB
    __shared__ __align__(16) float ilds[CI][TY + KH - 1][TX + KW - 1];

    const int tid   = threadIdx.x;
    const int x0    = blockIdx.x * TX;
    const int y0    = blockIdx.y * TY;
    const int bz    = blockIdx.z;        // b*2 + ohalf
    const int b     = bz >> 1;
    const int ohalf = bz & 1;

    // ---- stage img tile as float4 chunks: 8c * 12r * 9 float4 = 864 ----
    const float* imgb = img + (size_t)b * CI * HH * WW;
    #pragma unroll
    for (int it = 0; it < 2; ++it) {
        const int idx = tid + it * THREADS;
        if (idx < 864) {
            const int c   = idx / 108;
            const int rem = idx - c * 108;
            const int r   = rem / 9;
            const int f4  = rem - r * 9;
            const int gy = y0 + r;
            const int gx = x0 + f4 * 4;
            float4 v;
            if (gy < HH && gx < WW) {
                v = *(const float4*)&imgb[(c * HH + gy) * WW + gx];
            } else {
                v.x = v.y = v.z = v.w = -INFINITY;
            }
            *(float4*)&ilds[c][r][f4 * 4] = v;
        }
    }
    __syncthreads();

    const int tx = tid & 7;          // 4 px each
    const int ty = (tid >> 3) & 7;   // output row
    // one wave-uniform output channel per wave
    const int o = __builtin_amdgcn_readfirstlane(ohalf * 8 + (tid >> 6));

    const float* wp = kern + (size_t)o * (CI * KH * KW);

    float acc[4];
    #pragma unroll
    for (int p = 0; p < 4; ++p) acc[p] = -INFINITY;

    #pragma unroll 1
    for (int c = 0; c < CI; ++c) {
        // hoist this channel's 25 weights (uniform -> clustered s_load)
        float w[25];
        #pragma unroll
        for (int t = 0; t < 25; ++t) w[t] = wp[c * 25 + t];
        // preload this channel's img window (10 ds_read_b128)
        float4 va[5], vb[5];
        #pragma unroll
        for (int i = 0; i < KH; ++i) {
            const float* vp = &ilds[c][ty + i][tx * 4];
            va[i] = *(const float4*)vp;
            vb[i] = *(const float4*)(vp + 4);
        }
        // pure-VALU compute: per (i,p): 5 add + 2 max3 + 1 max
        #pragma unroll
        for (int i = 0; i < KH; ++i) {
            const float v[8] = {va[i].x, va[i].y, va[i].z, va[i].w,
                                vb[i].x, vb[i].y, vb[i].z, vb[i].w};
            #pragma unroll
            for (int p = 0; p < 4; ++p) {
                float T[5];
                #pragma unroll
                for (int j = 0; j < KW; ++j) {
                    const int wi = (4 - i) * KW + (4 - j);   // flipped tap
                    T[j] = v[p + j] + w[wi];
                }
                const float m0 = fmaxf(fmaxf(acc[p], T[0]), T[1]);  // v_max3
                const float m1 = fmaxf(fmaxf(T[2], T[3]), T[4]);    // v_max3
                acc[p] = fmaxf(m0, m1);
            }
        }
    }

    // ---- write out: one float4 ----
    const int y = y0 + ty;
    const int x = x0 + tx * 4;
    if (y < HO && x < WO) {
        float4 s;
        s.x = acc[0]; s.y = acc[1]; s.z = acc[2]; s.w = acc[3];
        *(float4*)&out[(((size_t)b * CO + o) * HO + y) * WO + x] = s;
    }
}

extern "C" void kernel_launch(void* const* d_in, const int* in_sizes, int n_in,
                              void* d_out, int out_size, void* d_ws, size_t ws_size,
                              hipStream_t stream)
{
    const float* img  = (const float*)d_in[0];
    const float* kern = (const float*)d_in[1];
    float* out = (float*)d_out;

    dim3 grid((WO + TX - 1) / TX, (HO + TY - 1) / TY, B_ * 2);  // 4 x 16 x 8 = 512 blocks
    dim3 block(THREADS);
    maxplus_conv4<<<grid, block, 0, stream>>>(img, kern, out);
}